// Round 1
// baseline (553.248 us; speedup 1.0000x reference)
//
#include <hip/hip_runtime.h>
#include <stdint.h>

using bf16x8 = __attribute__((ext_vector_type(8))) __bf16;
using f32x4  = __attribute__((ext_vector_type(4))) float;

#define AS1 __attribute__((address_space(1)))
#define AS3 __attribute__((address_space(3)))

// ---------------- workspace layout (bytes) ----------------
constexpr size_t OFF_WCAT  = 0;                               // [1536][768] bf16
constexpr size_t OFF_WPROJ = OFF_WCAT  + (size_t)1536*768*2;  // [512][512] bf16
constexpr size_t OFF_WOUT  = OFF_WPROJ + (size_t)512*512*2;   // [256][512] bf16 (padded)
constexpr size_t OFF_BR    = OFF_WOUT  + (size_t)256*512*2;   // [512] f32
constexpr size_t OFF_BZ    = OFF_BR    + 512*4;
constexpr size_t OFF_BIN   = OFF_BZ    + 512*4;
constexpr size_t OFF_BHN   = OFF_BIN   + 512*4;
constexpr size_t OFF_BPROJ = OFF_BHN   + 512*4;
constexpr size_t OFF_BOUT  = OFF_BPROJ + 512*4;               // [256] f32 (padded)
constexpr size_t OFF_XEMB  = OFF_BOUT  + 256*4;               // [14][8192][256] bf16
constexpr size_t OFF_HS    = OFF_XEMB  + (size_t)14*8192*256*2; // [15][8192][512] bf16
constexpr size_t OFF_H0    = OFF_HS    + (size_t)15*8192*512*2; // [8192][512] f32
constexpr size_t OFF_H1    = OFF_H0    + (size_t)8192*512*4;
constexpr size_t WS_NEED   = OFF_H1    + (size_t)8192*512*4;  // ~211 MB

// ---------------- helpers ----------------
__device__ __forceinline__ short f2bf(float f) {
  union { float f; unsigned u; } v; v.f = f;
  unsigned u = v.u;
  u += 0x7FFFu + ((u >> 16) & 1u);   // RNE
  return (short)(u >> 16);
}
__device__ __forceinline__ float sigm(float x) { return 1.f / (1.f + __expf(-x)); }
__device__ __forceinline__ float tanh_fast(float x) {
  x = fminf(fmaxf(x, -15.f), 15.f);
  float e = __expf(-2.f * x);
  return (1.f - e) / (1.f + e);
}

// Stage ROWS x 64(bf16) tile: linear LDS dest, XOR-swizzled per-lane global source
// (guide rule #21: linear dest + inverse-swz source + swz on read).
template<int ROWS>
__device__ __forceinline__ void stage_tile(const short* __restrict__ src, size_t row0,
                                           int stride, int k0, char* lds, int tid) {
  const int w = tid >> 6;
  const int lane = tid & 63;
#pragma unroll
  for (int s = 0; s < ROWS / 32; ++s) {
    const int rowbase = s * 32 + w * 8;            // wave-uniform
    const int row = rowbase + (lane >> 3);
    const int colE = ((lane & 7) ^ (row & 7)) * 8; // pre-swizzled source column
    const short* g = src + (row0 + (size_t)row) * (size_t)stride + k0 + colE;
    __builtin_amdgcn_global_load_lds((const AS1 int*)g, (AS3 int*)(lds + rowbase * 128),
                                     16, 0, 0);
  }
}

// Read a 16x32 MFMA fragment (8 bf16/lane) with the matching XOR swizzle.
__device__ __forceinline__ bf16x8 read_frag(const char* lds, int row, int ks, int lane) {
  const int kb = ks * 64 + ((lane >> 4) << 4);
  return *(const bf16x8*)(lds + row * 128 + (kb ^ ((row & 7) << 4)));
}

// ---------------- prep: pack weights/biases ----------------
__global__ void prep_kernel(const float* __restrict__ W_proj, const float* __restrict__ b_proj,
                            const float* __restrict__ W_ih, const float* __restrict__ W_hh,
                            const float* __restrict__ b_ih, const float* __restrict__ b_hh,
                            const float* __restrict__ W_out, const float* __restrict__ b_out,
                            short* __restrict__ wcat, short* __restrict__ wproj,
                            short* __restrict__ wout,
                            float* __restrict__ br, float* __restrict__ bz,
                            float* __restrict__ bin, float* __restrict__ bhn,
                            float* __restrict__ bproj, float* __restrict__ bout) {
  const int total = 1536*768 + 512*512 + 256*512 + 512*4 + 512 + 256;
  const int stride = gridDim.x * blockDim.x;
  for (int i = blockIdx.x * blockDim.x + threadIdx.x; i < total; i += stride) {
    int j = i;
    if (j < 1536*768) {
      int r = j / 768, c = j % 768;
      float v = (c < 256) ? W_ih[r*256 + c] : W_hh[r*512 + (c - 256)];
      wcat[j] = f2bf(v);
      continue;
    }
    j -= 1536*768;
    if (j < 512*512) { wproj[j] = f2bf(W_proj[j]); continue; }
    j -= 512*512;
    if (j < 256*512) {
      int r = j / 512, c = j % 512;
      wout[j] = f2bf(r < 193 ? W_out[r*512 + c] : 0.f);
      continue;
    }
    j -= 256*512;
    if (j < 512) { br[j] = b_ih[j] + b_hh[j]; continue; }
    j -= 512;
    if (j < 512) { bz[j] = b_ih[512 + j] + b_hh[512 + j]; continue; }
    j -= 512;
    if (j < 512) { bin[j] = b_ih[1024 + j]; continue; }
    j -= 512;
    if (j < 512) { bhn[j] = b_hh[1024 + j]; continue; }
    j -= 512;
    if (j < 512) { bproj[j] = b_proj[j]; continue; }
    j -= 512;
    bout[j] = (j < 193) ? b_out[j] : 0.f;
  }
}

// ---------------- embeddings + img -> bf16 ----------------
__global__ void embed_kernel(const float* __restrict__ emb, const int* __restrict__ text,
                             const float* __restrict__ img,
                             short* __restrict__ xemb, short* __restrict__ imgbf) {
  const int n1 = 14 * 8192 * 64;  // 4 elems each
  const int n2 = 8192 * 128;
  const int stride = gridDim.x * blockDim.x;
  for (int i = blockIdx.x * blockDim.x + threadIdx.x; i < n1 + n2; i += stride) {
    if (i < n1) {
      const int e4 = i & 63;
      const int bt = i >> 6;
      const int b = bt & 8191;
      const int t = bt >> 13;
      const int tok = text[b * 15 + t];
      const float4 v = *(const float4*)(emb + (size_t)tok * 256 + e4 * 4);
      short4 o; o.x = f2bf(v.x); o.y = f2bf(v.y); o.z = f2bf(v.z); o.w = f2bf(v.w);
      *(short4*)(xemb + (size_t)i * 4) = o;
    } else {
      const int k = i - n1;
      const float4 v = *(const float4*)(img + (size_t)k * 4);
      short4 o; o.x = f2bf(v.x); o.y = f2bf(v.y); o.z = f2bf(v.z); o.w = f2bf(v.w);
      *(short4*)(imgbf + (size_t)k * 4) = o;
    }
  }
}

// ---------------- plain GEMM (MODE 0: h0 projection, MODE 1: vocab out) ----------------
// C[M][64-tile] = A[M][512] @ B[N][512]^T + bias,  128x64 tile, 4 waves (2x2)
template<int MODE>
__global__ __launch_bounds__(256, 2)
void gemm_kernel(const short* __restrict__ A, const short* __restrict__ Bw,
                 const float* __restrict__ bias, float* __restrict__ out_f,
                 short* __restrict__ out_bf) {
  __shared__ __align__(16) char smem[128*128 + 64*128];
  char* ldsA = smem;
  char* ldsB = smem + 128*128;
  const int tid = threadIdx.x;
  const int lane = tid & 63;
  const int w = tid >> 6;
  const int wr = w >> 1, wc = w & 1;
  const size_t m0 = (size_t)blockIdx.x * 128;
  const int j0 = blockIdx.y * 64;

  f32x4 acc[4][2];
#pragma unroll
  for (int a = 0; a < 4; ++a)
#pragma unroll
    for (int b = 0; b < 2; ++b) acc[a][b] = f32x4{0.f, 0.f, 0.f, 0.f};

  for (int it = 0; it < 8; ++it) {
    const int k0 = it * 64;
    __syncthreads();
    stage_tile<128>(A, m0, 512, k0, ldsA, tid);
    stage_tile<64>(Bw, (size_t)j0, 512, k0, ldsB, tid);
    __syncthreads();
#pragma unroll
    for (int ks = 0; ks < 2; ++ks) {
      bf16x8 af[4];
#pragma unroll
      for (int mi = 0; mi < 4; ++mi)
        af[mi] = read_frag(ldsA, wr*64 + mi*16 + (lane & 15), ks, lane);
#pragma unroll
      for (int ji = 0; ji < 2; ++ji) {
        bf16x8 bfm = read_frag(ldsB, wc*32 + ji*16 + (lane & 15), ks, lane);
#pragma unroll
        for (int mi = 0; mi < 4; ++mi)
          acc[mi][ji] = __builtin_amdgcn_mfma_f32_16x16x32_bf16(af[mi], bfm, acc[mi][ji], 0, 0, 0);
      }
    }
  }
#pragma unroll
  for (int ji = 0; ji < 2; ++ji) {
    const int j = j0 + wc*32 + ji*16 + (lane & 15);
    const float bj = bias[j];
#pragma unroll
    for (int mi = 0; mi < 4; ++mi) {
#pragma unroll
      for (int i = 0; i < 4; ++i) {
        const size_t m = m0 + wr*64 + mi*16 + ((lane >> 4) * 4) + i;
        const float v = acc[mi][ji][i] + bj;
        if (MODE == 0) {
          out_f[m * 512 + j] = v;
          out_bf[m * 512 + j] = f2bf(v);
        } else {
          if (j < 193) {
            const size_t b = m & 8191, t = m >> 13;
            out_f[(b * 14 + t) * 193 + j] = v;
          }
        }
      }
    }
  }
}

// ---------------- fused GRU step ----------------
// gates = [x_t | h] @ Wcat^T ; 4 accumulator sets: r,z over K=768; i_n (k<256), h_n (k>=256)
__global__ __launch_bounds__(256, 2)
void gate_kernel(const short* __restrict__ X, const short* __restrict__ Hbf,
                 const short* __restrict__ Wcat,
                 const float* __restrict__ br, const float* __restrict__ bz,
                 const float* __restrict__ bin, const float* __restrict__ bhn,
                 const float* __restrict__ h_cur, float* __restrict__ h_nxt,
                 short* __restrict__ hs_out) {
  __shared__ __align__(16) char smem[128*128 + 192*128];
  char* ldsA = smem;
  char* ldsB = smem + 128*128;
  const int tid = threadIdx.x;
  const int lane = tid & 63;
  const int w = tid >> 6;
  const int wr = w >> 1, wc = w & 1;
  const size_t m0 = (size_t)blockIdx.x * 128;
  const int j0 = blockIdx.y * 64;

  f32x4 acc_r[4][2], acc_z[4][2], acc_in[4][2], acc_hn[4][2];
#pragma unroll
  for (int a = 0; a < 4; ++a)
#pragma unroll
    for (int b = 0; b < 2; ++b) {
      acc_r[a][b] = f32x4{0.f, 0.f, 0.f, 0.f};
      acc_z[a][b] = f32x4{0.f, 0.f, 0.f, 0.f};
      acc_in[a][b] = f32x4{0.f, 0.f, 0.f, 0.f};
      acc_hn[a][b] = f32x4{0.f, 0.f, 0.f, 0.f};
    }

  for (int it = 0; it < 12; ++it) {
    const int k0 = it * 64;
    __syncthreads();
    if (k0 < 256) stage_tile<128>(X, m0, 256, k0, ldsA, tid);
    else          stage_tile<128>(Hbf, m0, 512, k0 - 256, ldsA, tid);
#pragma unroll
    for (int g = 0; g < 3; ++g)
      stage_tile<64>(Wcat, (size_t)(g * 512 + j0), 768, k0, ldsB + g * 64 * 128, tid);
    __syncthreads();
    const bool isx = (k0 < 256);
#pragma unroll
    for (int ks = 0; ks < 2; ++ks) {
      bf16x8 af[4];
#pragma unroll
      for (int mi = 0; mi < 4; ++mi)
        af[mi] = read_frag(ldsA, wr*64 + mi*16 + (lane & 15), ks, lane);
#pragma unroll
      for (int ji = 0; ji < 2; ++ji) {
        const int nb = wc*32 + ji*16 + (lane & 15);
        bf16x8 b_r = read_frag(ldsB,            nb, ks, lane);
        bf16x8 b_z = read_frag(ldsB + 64*128,   nb, ks, lane);
        bf16x8 b_n = read_frag(ldsB + 128*128,  nb, ks, lane);
#pragma unroll
        for (int mi = 0; mi < 4; ++mi) {
          acc_r[mi][ji] = __builtin_amdgcn_mfma_f32_16x16x32_bf16(af[mi], b_r, acc_r[mi][ji], 0, 0, 0);
          acc_z[mi][ji] = __builtin_amdgcn_mfma_f32_16x16x32_bf16(af[mi], b_z, acc_z[mi][ji], 0, 0, 0);
        }
        if (isx) {
#pragma unroll
          for (int mi = 0; mi < 4; ++mi)
            acc_in[mi][ji] = __builtin_amdgcn_mfma_f32_16x16x32_bf16(af[mi], b_n, acc_in[mi][ji], 0, 0, 0);
        } else {
#pragma unroll
          for (int mi = 0; mi < 4; ++mi)
            acc_hn[mi][ji] = __builtin_amdgcn_mfma_f32_16x16x32_bf16(af[mi], b_n, acc_hn[mi][ji], 0, 0, 0);
        }
      }
    }
  }
  // epilogue: gate math + h update (thread-local: all 4 accs share (m,j) mapping)
#pragma unroll
  for (int ji = 0; ji < 2; ++ji) {
    const int j = j0 + wc*32 + ji*16 + (lane & 15);
    const float vbr = br[j], vbz = bz[j], vbin = bin[j], vbhn = bhn[j];
#pragma unroll
    for (int mi = 0; mi < 4; ++mi) {
#pragma unroll
      for (int i = 0; i < 4; ++i) {
        const size_t m = m0 + wr*64 + mi*16 + ((lane >> 4) * 4) + i;
        const float r = sigm(acc_r[mi][ji][i] + vbr);
        const float z = sigm(acc_z[mi][ji][i] + vbz);
        const float n = tanh_fast(acc_in[mi][ji][i] + vbin + r * (acc_hn[mi][ji][i] + vbhn));
        const float hv = (1.f - z) * n + z * h_cur[m * 512 + j];
        h_nxt[m * 512 + j] = hv;
        hs_out[m * 512 + j] = f2bf(hv);
      }
    }
  }
}

// ---------------- launch ----------------
extern "C" void kernel_launch(void* const* d_in, const int* in_sizes, int n_in,
                              void* d_out, int out_size, void* d_ws, size_t ws_size,
                              hipStream_t stream) {
  (void)in_sizes; (void)n_in; (void)out_size;
  if (ws_size < WS_NEED) return;

  const float* img    = (const float*)d_in[0];
  const int*   text   = (const int*)  d_in[1];
  const float* emb    = (const float*)d_in[2];
  const float* W_proj = (const float*)d_in[3];
  const float* b_proj = (const float*)d_in[4];
  const float* W_ih   = (const float*)d_in[5];
  const float* W_hh   = (const float*)d_in[6];
  const float* b_ih   = (const float*)d_in[7];
  const float* b_hh   = (const float*)d_in[8];
  const float* W_out  = (const float*)d_in[9];
  const float* b_out  = (const float*)d_in[10];
  float* out = (float*)d_out;
  char* ws = (char*)d_ws;

  short* wcat  = (short*)(ws + OFF_WCAT);
  short* wproj = (short*)(ws + OFF_WPROJ);
  short* wout  = (short*)(ws + OFF_WOUT);
  float* br    = (float*)(ws + OFF_BR);
  float* bz    = (float*)(ws + OFF_BZ);
  float* bin   = (float*)(ws + OFF_BIN);
  float* bhn   = (float*)(ws + OFF_BHN);
  float* bproj = (float*)(ws + OFF_BPROJ);
  float* bout  = (float*)(ws + OFF_BOUT);
  short* xemb  = (short*)(ws + OFF_XEMB);
  short* hs    = (short*)(ws + OFF_HS);
  float* hbuf0 = (float*)(ws + OFF_H0);
  float* hbuf1 = (float*)(ws + OFF_H1);
  short* imgbf = (short*)hbuf1;  // alias: img bf16 dead before hbuf1 first written (t=0 h_nxt)

  prep_kernel<<<1024, 256, 0, stream>>>(W_proj, b_proj, W_ih, W_hh, b_ih, b_hh, W_out, b_out,
                                        wcat, wproj, wout, br, bz, bin, bhn, bproj, bout);
  embed_kernel<<<2048, 256, 0, stream>>>(emb, text, img, xemb, imgbf);

  // h0 = img @ W_proj^T + b_proj  -> hbuf0 (f32) + hs[0] (bf16)
  gemm_kernel<0><<<dim3(64, 8), 256, 0, stream>>>(imgbf, wproj, bproj, hbuf0, hs);

  for (int t = 0; t < 14; ++t) {
    const short* Xt = xemb + (size_t)t * 8192 * 256;
    const short* Hb = hs + (size_t)t * 8192 * 512;
    short* Ho       = hs + (size_t)(t + 1) * 8192 * 512;
    float* hc = (t & 1) ? hbuf1 : hbuf0;
    float* hn = (t & 1) ? hbuf0 : hbuf1;
    gate_kernel<<<dim3(64, 8), 256, 0, stream>>>(Xt, Hb, wcat, br, bz, bin, bhn, hc, hn, Ho);
  }

  // preds = hs[1..14] @ W_out^T + b_out  -> out[b][t][v]
  gemm_kernel<1><<<dim3(896, 4), 256, 0, stream>>>(hs + (size_t)8192 * 512, wout, bout,
                                                   out, nullptr);
}

// Round 2
// 492.309 us; speedup vs baseline: 1.1238x; 1.1238x over previous
//
#include <hip/hip_runtime.h>
#include <stdint.h>

using bf16x8 = __attribute__((ext_vector_type(8))) __bf16;
using f32x4  = __attribute__((ext_vector_type(4))) float;

#define AS1 __attribute__((address_space(1)))
#define AS3 __attribute__((address_space(3)))

// ---------------- workspace layout (bytes) ----------------
constexpr size_t OFF_WCAT  = 0;                               // [1536][768] bf16
constexpr size_t OFF_WPROJ = OFF_WCAT  + (size_t)1536*768*2;  // [512][512] bf16
constexpr size_t OFF_WOUT  = OFF_WPROJ + (size_t)512*512*2;   // [256][512] bf16 (padded)
constexpr size_t OFF_BR    = OFF_WOUT  + (size_t)256*512*2;   // [512] f32
constexpr size_t OFF_BZ    = OFF_BR    + 512*4;
constexpr size_t OFF_BIN   = OFF_BZ    + 512*4;
constexpr size_t OFF_BHN   = OFF_BIN   + 512*4;
constexpr size_t OFF_BPROJ = OFF_BHN   + 512*4;
constexpr size_t OFF_BOUT  = OFF_BPROJ + 512*4;               // [256] f32 (padded)
constexpr size_t OFF_XEMB  = OFF_BOUT  + 256*4;               // [14][8192][256] bf16
constexpr size_t OFF_HS    = OFF_XEMB  + (size_t)14*8192*256*2; // [15][8192][512] bf16
constexpr size_t OFF_IMG   = OFF_HS    + (size_t)15*8192*512*2; // [8192][512] bf16
constexpr size_t WS_NEED   = OFF_IMG   + (size_t)8192*512*2;  // ~195 MB

// ---------------- helpers ----------------
__device__ __forceinline__ short f2bf(float f) {
  union { float f; unsigned u; } v; v.f = f;
  unsigned u = v.u;
  u += 0x7FFFu + ((u >> 16) & 1u);   // RNE
  return (short)(u >> 16);
}
__device__ __forceinline__ float bf2f(short s) {
  union { float f; unsigned u; } v; v.u = ((unsigned)(unsigned short)s) << 16;
  return v.f;
}
__device__ __forceinline__ float sigm(float x) { return 1.f / (1.f + __expf(-x)); }
__device__ __forceinline__ float tanh_fast(float x) {
  x = fminf(fmaxf(x, -15.f), 15.f);
  float e = __expf(-2.f * x);
  return (1.f - e) / (1.f + e);
}

// Stage ROWS x 64(bf16) tile: linear LDS dest, XOR-swizzled per-lane global source
// (rule #21: linear dest + inverse-swz source + swz on read).
template<int ROWS, int WAVES>
__device__ __forceinline__ void stage_tile(const short* __restrict__ src, size_t row0,
                                           int stride, int k0, char* lds, int tid) {
  const int w = tid >> 6;
  const int lane = tid & 63;
#pragma unroll
  for (int s = 0; s < ROWS / (8 * WAVES); ++s) {
    const int rowbase = s * (8 * WAVES) + w * 8;   // wave-uniform
    const int row = rowbase + (lane >> 3);
    const int colE = ((lane & 7) ^ (row & 7)) * 8; // pre-swizzled source column
    const short* g = src + (row0 + (size_t)row) * (size_t)stride + k0 + colE;
    __builtin_amdgcn_global_load_lds((const AS1 int*)g, (AS3 int*)(lds + rowbase * 128),
                                     16, 0, 0);
  }
}

// Read a 16x32 MFMA fragment (8 bf16/lane) with the matching XOR swizzle.
__device__ __forceinline__ bf16x8 read_frag(const char* lds, int row, int ks, int lane) {
  const int kb = ks * 64 + ((lane >> 4) << 4);
  return *(const bf16x8*)(lds + row * 128 + (kb ^ ((row & 7) << 4)));
}

// ---------------- prep: pack weights/biases ----------------
__global__ void prep_kernel(const float* __restrict__ W_proj, const float* __restrict__ b_proj,
                            const float* __restrict__ W_ih, const float* __restrict__ W_hh,
                            const float* __restrict__ b_ih, const float* __restrict__ b_hh,
                            const float* __restrict__ W_out, const float* __restrict__ b_out,
                            short* __restrict__ wcat, short* __restrict__ wproj,
                            short* __restrict__ wout,
                            float* __restrict__ br, float* __restrict__ bz,
                            float* __restrict__ bin, float* __restrict__ bhn,
                            float* __restrict__ bproj, float* __restrict__ bout) {
  const int total = 1536*768 + 512*512 + 256*512 + 512*4 + 512 + 256;
  const int stride = gridDim.x * blockDim.x;
  for (int i = blockIdx.x * blockDim.x + threadIdx.x; i < total; i += stride) {
    int j = i;
    if (j < 1536*768) {
      int r = j / 768, c = j % 768;
      float v = (c < 256) ? W_ih[r*256 + c] : W_hh[r*512 + (c - 256)];
      wcat[j] = f2bf(v);
      continue;
    }
    j -= 1536*768;
    if (j < 512*512) { wproj[j] = f2bf(W_proj[j]); continue; }
    j -= 512*512;
    if (j < 256*512) {
      int r = j / 512, c = j % 512;
      wout[j] = f2bf(r < 193 ? W_out[r*512 + c] : 0.f);
      continue;
    }
    j -= 256*512;
    if (j < 512) { br[j] = b_ih[j] + b_hh[j]; continue; }
    j -= 512;
    if (j < 512) { bz[j] = b_ih[512 + j] + b_hh[512 + j]; continue; }
    j -= 512;
    if (j < 512) { bin[j] = b_ih[1024 + j]; continue; }
    j -= 512;
    if (j < 512) { bhn[j] = b_hh[1024 + j]; continue; }
    j -= 512;
    if (j < 512) { bproj[j] = b_proj[j]; continue; }
    j -= 512;
    bout[j] = (j < 193) ? b_out[j] : 0.f;
  }
}

// ---------------- embeddings + img -> bf16 ----------------
__global__ void embed_kernel(const float* __restrict__ emb, const int* __restrict__ text,
                             const float* __restrict__ img,
                             short* __restrict__ xemb, short* __restrict__ imgbf) {
  const int n1 = 14 * 8192 * 64;  // 4 elems each
  const int n2 = 8192 * 128;
  const int stride = gridDim.x * blockDim.x;
  for (int i = blockIdx.x * blockDim.x + threadIdx.x; i < n1 + n2; i += stride) {
    if (i < n1) {
      const int e4 = i & 63;
      const int bt = i >> 6;
      const int b = bt & 8191;
      const int t = bt >> 13;
      const int tok = text[b * 15 + t];
      const float4 v = *(const float4*)(emb + (size_t)tok * 256 + e4 * 4);
      short4 o; o.x = f2bf(v.x); o.y = f2bf(v.y); o.z = f2bf(v.z); o.w = f2bf(v.w);
      *(short4*)(xemb + (size_t)i * 4) = o;
    } else {
      const int k = i - n1;
      const float4 v = *(const float4*)(img + (size_t)k * 4);
      short4 o; o.x = f2bf(v.x); o.y = f2bf(v.y); o.z = f2bf(v.z); o.w = f2bf(v.w);
      *(short4*)(imgbf + (size_t)k * 4) = o;
    }
  }
}

// ---------------- GEMM, 8 waves, 128M x 256N tile, K=512 ----------------
// MODE 0: h0 projection (write bf16 hs).  MODE 1: vocab out (write f32 scattered).
template<int MODE>
__global__ __launch_bounds__(512, 1)
void gemm_kernel(const short* __restrict__ A, const short* __restrict__ Bw,
                 const float* __restrict__ bias, float* __restrict__ out_f,
                 short* __restrict__ out_bf, int j0) {
  __shared__ __align__(16) char smem[128*128 + 256*128];   // 48 KB
  char* ldsA = smem;
  char* ldsB = smem + 128*128;
  const int tid = threadIdx.x;
  const int lane = tid & 63;
  const int w = tid >> 6;
  const int wr = w >> 2, wc = w & 3;   // 2 x 4 wave grid
  const size_t m0 = (size_t)blockIdx.x * 128;

  f32x4 acc[4][4];
#pragma unroll
  for (int a = 0; a < 4; ++a)
#pragma unroll
    for (int b = 0; b < 4; ++b) acc[a][b] = f32x4{0.f, 0.f, 0.f, 0.f};

  for (int it = 0; it < 8; ++it) {
    const int k0 = it * 64;
    __syncthreads();
    stage_tile<128, 8>(A, m0, 512, k0, ldsA, tid);
    stage_tile<256, 8>(Bw, (size_t)j0, 512, k0, ldsB, tid);
    __syncthreads();
#pragma unroll
    for (int ks = 0; ks < 2; ++ks) {
      bf16x8 af[4];
#pragma unroll
      for (int mi = 0; mi < 4; ++mi)
        af[mi] = read_frag(ldsA, wr*64 + mi*16 + (lane & 15), ks, lane);
#pragma unroll
      for (int ji = 0; ji < 4; ++ji) {
        bf16x8 bfm = read_frag(ldsB, wc*64 + ji*16 + (lane & 15), ks, lane);
#pragma unroll
        for (int mi = 0; mi < 4; ++mi)
          acc[mi][ji] = __builtin_amdgcn_mfma_f32_16x16x32_bf16(af[mi], bfm, acc[mi][ji], 0, 0, 0);
      }
    }
  }
#pragma unroll
  for (int ji = 0; ji < 4; ++ji) {
    const int j = j0 + wc*64 + ji*16 + (lane & 15);
    const float bj = bias[j - j0 + (MODE == 0 ? j0 : 0)]; // bias indexed by padded col
#pragma unroll
    for (int mi = 0; mi < 4; ++mi) {
#pragma unroll
      for (int i = 0; i < 4; ++i) {
        const size_t m = m0 + wr*64 + mi*16 + ((lane >> 4) * 4) + i;
        const float v = acc[mi][ji][i] + bj;
        if (MODE == 0) {
          out_bf[m * 512 + j] = f2bf(v);
        } else {
          if (j < 193) {
            const size_t b = m & 8191, t = m >> 13;
            out_f[(b * 14 + t) * 193 + j] = v;
          }
        }
      }
    }
  }
}

// ---------------- fused GRU step ----------------
// gates = [x_t | h] @ Wcat^T ; 4 accumulator sets: r,z over K=768; i_n (k<256), h_n (k>=256)
// h carried in bf16 (hs slab); epilogue re-reads h_{t-1} from the L2-hot A-operand slab.
__global__ __launch_bounds__(256, 2)
void gate_kernel(const short* __restrict__ X, const short* __restrict__ Hbf,
                 const short* __restrict__ Wcat,
                 const float* __restrict__ br, const float* __restrict__ bz,
                 const float* __restrict__ bin, const float* __restrict__ bhn,
                 short* __restrict__ hs_out) {
  __shared__ __align__(16) char smem[128*128 + 192*128];
  char* ldsA = smem;
  char* ldsB = smem + 128*128;
  const int tid = threadIdx.x;
  const int lane = tid & 63;
  const int w = tid >> 6;
  const int wr = w >> 1, wc = w & 1;
  const size_t m0 = (size_t)blockIdx.x * 128;
  const int j0 = blockIdx.y * 64;

  f32x4 acc_r[4][2], acc_z[4][2], acc_in[4][2], acc_hn[4][2];
#pragma unroll
  for (int a = 0; a < 4; ++a)
#pragma unroll
    for (int b = 0; b < 2; ++b) {
      acc_r[a][b] = f32x4{0.f, 0.f, 0.f, 0.f};
      acc_z[a][b] = f32x4{0.f, 0.f, 0.f, 0.f};
      acc_in[a][b] = f32x4{0.f, 0.f, 0.f, 0.f};
      acc_hn[a][b] = f32x4{0.f, 0.f, 0.f, 0.f};
    }

  for (int it = 0; it < 12; ++it) {
    const int k0 = it * 64;
    __syncthreads();
    if (k0 < 256) stage_tile<128, 4>(X, m0, 256, k0, ldsA, tid);
    else          stage_tile<128, 4>(Hbf, m0, 512, k0 - 256, ldsA, tid);
#pragma unroll
    for (int g = 0; g < 3; ++g)
      stage_tile<64, 4>(Wcat, (size_t)(g * 512 + j0), 768, k0, ldsB + g * 64 * 128, tid);
    __syncthreads();
    const bool isx = (k0 < 256);
#pragma unroll
    for (int ks = 0; ks < 2; ++ks) {
      bf16x8 af[4];
#pragma unroll
      for (int mi = 0; mi < 4; ++mi)
        af[mi] = read_frag(ldsA, wr*64 + mi*16 + (lane & 15), ks, lane);
#pragma unroll
      for (int ji = 0; ji < 2; ++ji) {
        const int nb = wc*32 + ji*16 + (lane & 15);
        bf16x8 b_r = read_frag(ldsB,            nb, ks, lane);
        bf16x8 b_z = read_frag(ldsB + 64*128,   nb, ks, lane);
        bf16x8 b_n = read_frag(ldsB + 128*128,  nb, ks, lane);
#pragma unroll
        for (int mi = 0; mi < 4; ++mi) {
          acc_r[mi][ji] = __builtin_amdgcn_mfma_f32_16x16x32_bf16(af[mi], b_r, acc_r[mi][ji], 0, 0, 0);
          acc_z[mi][ji] = __builtin_amdgcn_mfma_f32_16x16x32_bf16(af[mi], b_z, acc_z[mi][ji], 0, 0, 0);
        }
        if (isx) {
#pragma unroll
          for (int mi = 0; mi < 4; ++mi)
            acc_in[mi][ji] = __builtin_amdgcn_mfma_f32_16x16x32_bf16(af[mi], b_n, acc_in[mi][ji], 0, 0, 0);
        } else {
#pragma unroll
          for (int mi = 0; mi < 4; ++mi)
            acc_hn[mi][ji] = __builtin_amdgcn_mfma_f32_16x16x32_bf16(af[mi], b_n, acc_hn[mi][ji], 0, 0, 0);
        }
      }
    }
  }
  // epilogue: gate math + h update (thread-local: all 4 accs share (m,j) mapping)
#pragma unroll
  for (int ji = 0; ji < 2; ++ji) {
    const int j = j0 + wc*32 + ji*16 + (lane & 15);
    const float vbr = br[j], vbz = bz[j], vbin = bin[j], vbhn = bhn[j];
#pragma unroll
    for (int mi = 0; mi < 4; ++mi) {
#pragma unroll
      for (int i = 0; i < 4; ++i) {
        const size_t m = m0 + wr*64 + mi*16 + ((lane >> 4) * 4) + i;
        const float r = sigm(acc_r[mi][ji][i] + vbr);
        const float z = sigm(acc_z[mi][ji][i] + vbz);
        const float n = tanh_fast(acc_in[mi][ji][i] + vbin + r * (acc_hn[mi][ji][i] + vbhn));
        const float hold = bf2f(Hbf[m * 512 + j]);
        const float hv = (1.f - z) * n + z * hold;
        hs_out[m * 512 + j] = f2bf(hv);
      }
    }
  }
}

// ---------------- launch ----------------
extern "C" void kernel_launch(void* const* d_in, const int* in_sizes, int n_in,
                              void* d_out, int out_size, void* d_ws, size_t ws_size,
                              hipStream_t stream) {
  (void)in_sizes; (void)n_in; (void)out_size;
  if (ws_size < WS_NEED) return;

  const float* img    = (const float*)d_in[0];
  const int*   text   = (const int*)  d_in[1];
  const float* emb    = (const float*)d_in[2];
  const float* W_proj = (const float*)d_in[3];
  const float* b_proj = (const float*)d_in[4];
  const float* W_ih   = (const float*)d_in[5];
  const float* W_hh   = (const float*)d_in[6];
  const float* b_ih   = (const float*)d_in[7];
  const float* b_hh   = (const float*)d_in[8];
  const float* W_out  = (const float*)d_in[9];
  const float* b_out  = (const float*)d_in[10];
  float* out = (float*)d_out;
  char* ws = (char*)d_ws;

  short* wcat  = (short*)(ws + OFF_WCAT);
  short* wproj = (short*)(ws + OFF_WPROJ);
  short* wout  = (short*)(ws + OFF_WOUT);
  float* br    = (float*)(ws + OFF_BR);
  float* bz    = (float*)(ws + OFF_BZ);
  float* bin   = (float*)(ws + OFF_BIN);
  float* bhn   = (float*)(ws + OFF_BHN);
  float* bproj = (float*)(ws + OFF_BPROJ);
  float* bout  = (float*)(ws + OFF_BOUT);
  short* xemb  = (short*)(ws + OFF_XEMB);
  short* hs    = (short*)(ws + OFF_HS);
  short* imgbf = (short*)(ws + OFF_IMG);

  prep_kernel<<<1024, 256, 0, stream>>>(W_proj, b_proj, W_ih, W_hh, b_ih, b_hh, W_out, b_out,
                                        wcat, wproj, wout, br, bz, bin, bhn, bproj, bout);
  embed_kernel<<<2048, 256, 0, stream>>>(emb, text, img, xemb, imgbf);

  // h0 = img @ W_proj^T + b_proj  -> hs[0] (bf16); N=512 via two j-halves
  gemm_kernel<0><<<dim3(64, 1), 512, 0, stream>>>(imgbf, wproj, bproj, nullptr, hs, 0);
  gemm_kernel<0><<<dim3(64, 1), 512, 0, stream>>>(imgbf, wproj, bproj, nullptr, hs, 256);

  for (int t = 0; t < 14; ++t) {
    const short* Xt = xemb + (size_t)t * 8192 * 256;
    const short* Hb = hs + (size_t)t * 8192 * 512;
    short* Ho       = hs + (size_t)(t + 1) * 8192 * 512;
    gate_kernel<<<dim3(64, 8), 256, 0, stream>>>(Xt, Hb, wcat, br, bz, bin, bhn, Ho);
  }

  // preds = hs[1..14] @ W_out^T + b_out  -> out[b][t][v]; single N-pass (N=256 padded)
  gemm_kernel<1><<<dim3(896, 1), 512, 0, stream>>>(hs + (size_t)8192 * 512, wout, bout,
                                                   out, nullptr, 0);
}